// Round 1
// baseline (567.656 us; speedup 1.0000x reference)
//
#include <hip/hip_runtime.h>
#include <hip/hip_bf16.h>

// Segment enumeration: degrees 8,7,6,5,4 — each segment is 4096 contiguous
// floats of one polynomial row. counts: 8*4096, 8*512, 8*64, 8*8, 8*1.
#define OFF7 32768
#define OFF6 36864
#define OFF5 37376
#define OFF4 37440
#define NSEG 37448

__device__ __forceinline__ int swz(int t) { return t ^ ((t >> 3) & 7); }

__device__ __forceinline__ float4 mul4(float4 a, float4 b) {
    return make_float4(a.x * b.x, a.y * b.y, a.z * b.z, a.w * b.w);
}

// Big kernel: degrees 4..8. Tables T_k[idx] = float4 over 4 neurons of
// kron^k(x)[idx], stored at swizzled index (involution t^((t>>3)&7)) so the
// stride-64B ds_read_b128 pattern is bank-conflict-free.
__global__ __launch_bounds__(512, 4) void poly_big(
    const float* __restrict__ X,
    const float* __restrict__ c4, const float* __restrict__ c5,
    const float* __restrict__ c6, const float* __restrict__ c7,
    const float* __restrict__ c8, float* __restrict__ ws)
{
    __shared__ float4 T0[1], T1[8], T2[64], T3[512], T4[4096];
    __shared__ float part[32];
    const int tid = threadIdx.x;

    if (tid == 0) T0[0] = make_float4(1.f, 1.f, 1.f, 1.f);
    if (tid < 8)  T1[tid] = make_float4(X[tid], X[8 + tid], X[16 + tid], X[24 + tid]);
    if (tid < 32) part[tid] = 0.f;
    __syncthreads();
    if (tid < 64) T2[swz(tid)] = mul4(T1[tid >> 3], T1[tid & 7]);
    __syncthreads();
    if (tid < 512) T3[swz(tid)] = mul4(T2[swz(tid >> 3)], T1[tid & 7]);
    for (int t = tid; t < 4096; t += 512)
        T4[swz(t)] = mul4(T2[swz(t >> 6)], T2[swz(t & 63)]);
    __syncthreads();

    const int wid = (blockIdx.x * blockDim.x + tid) >> 6;
    const int W   = (gridDim.x * blockDim.x) >> 6;
    const int l   = tid & 63;

    for (int g = wid; g < NSEG; g += W) {
        const float* src; const float4* thiT; int p, hi;
        if (g < OFF7)      { p = g >> 12;               hi = g & 4095;  src = c8 + ((size_t)p << 24); thiT = T4; }
        else if (g < OFF6) { int s = g - OFF7; p = s >> 9; hi = s & 511; src = c7 + ((size_t)p << 21); thiT = T3; }
        else if (g < OFF5) { int s = g - OFF6; p = s >> 6; hi = s & 63;  src = c6 + ((size_t)p << 18); thiT = T2; }
        else if (g < OFF4) { int s = g - OFF5; p = s >> 3; hi = s & 7;   src = c5 + ((size_t)p << 15); thiT = T1; }
        else               { int s = g - OFF4; p = s;      hi = 0;       src = c4 + ((size_t)p << 12); thiT = T0; }
        const float4* src4 = (const float4*)(src + ((size_t)hi << 12));

        float4 acc = make_float4(0.f, 0.f, 0.f, 0.f);
        #pragma unroll
        for (int k = 0; k < 16; ++k) {
            float4 cv = src4[(k << 6) + l];
            int lo = ((k << 6) + l) << 2;
            float4 t0 = T4[swz(lo + 0)];
            float4 t1 = T4[swz(lo + 1)];
            float4 t2 = T4[swz(lo + 2)];
            float4 t3 = T4[swz(lo + 3)];
            acc.x = fmaf(cv.x, t0.x, acc.x); acc.x = fmaf(cv.y, t1.x, acc.x);
            acc.x = fmaf(cv.z, t2.x, acc.x); acc.x = fmaf(cv.w, t3.x, acc.x);
            acc.y = fmaf(cv.x, t0.y, acc.y); acc.y = fmaf(cv.y, t1.y, acc.y);
            acc.y = fmaf(cv.z, t2.y, acc.y); acc.y = fmaf(cv.w, t3.y, acc.y);
            acc.z = fmaf(cv.x, t0.z, acc.z); acc.z = fmaf(cv.y, t1.z, acc.z);
            acc.z = fmaf(cv.z, t2.z, acc.z); acc.z = fmaf(cv.w, t3.z, acc.z);
            acc.w = fmaf(cv.x, t0.w, acc.w); acc.w = fmaf(cv.y, t1.w, acc.w);
            acc.w = fmaf(cv.z, t2.w, acc.w); acc.w = fmaf(cv.w, t3.w, acc.w);
        }

        float4 th = thiT[swz(hi)];  // wave-uniform -> LDS broadcast
        float vx = acc.x * th.x, vy = acc.y * th.y, vz = acc.z * th.z, vw = acc.w * th.w;
        #pragma unroll
        for (int m = 32; m; m >>= 1) {
            vx += __shfl_xor(vx, m);
            vy += __shfl_xor(vy, m);
            vz += __shfl_xor(vz, m);
            vw += __shfl_xor(vw, m);
        }
        if (l == 0) {
            atomicAdd(&part[(p << 2) + 0], vx);
            atomicAdd(&part[(p << 2) + 1], vy);
            atomicAdd(&part[(p << 2) + 2], vz);
            atomicAdd(&part[(p << 2) + 3], vw);
        }
    }
    __syncthreads();
    // ws layout: [block][o] with o = neu*8 + p  (matches output layout)
    if (tid < 32) ws[(size_t)blockIdx.x * 32 + tid] = part[((tid & 7) << 2) + (tid >> 3)];
}

// Finalize: reduce block partials + bias + degrees 1..3.
__global__ __launch_bounds__(256) void poly_final(
    const float* __restrict__ X, const float* __restrict__ bias,
    const float* __restrict__ c1, const float* __restrict__ c2,
    const float* __restrict__ c3, const float* __restrict__ ws,
    int nblocks, float* __restrict__ out)
{
    __shared__ float xs[4][8];
    __shared__ float redA[8][32];
    __shared__ float redB[8][32][4];
    const int t = threadIdx.x;
    if (t < 32) xs[t >> 3][t & 7] = X[t];
    __syncthreads();

    // Phase A: sum the big-kernel partials. o = neu*8+p, 8 groups stride blocks.
    {
        int o = t & 31, g = t >> 5;
        float s = 0.f;
        for (int b = g; b < nblocks; b += 8) s += ws[(size_t)b * 32 + o];
        redA[g][o] = s;
    }
    // Phase B: degrees 1..3. p = t>>5, 32 lanes per polynomial.
    {
        int p = t >> 5, l = t & 31;
        float s0 = 0.f, s1 = 0.f, s2 = 0.f, s3 = 0.f;
        for (int i = l; i < 512; i += 32) {
            float cv = c3[(p << 9) + i];
            int d1 = (i >> 6) & 7, d2 = (i >> 3) & 7, d3 = i & 7;
            s0 = fmaf(cv, xs[0][d1] * xs[0][d2] * xs[0][d3], s0);
            s1 = fmaf(cv, xs[1][d1] * xs[1][d2] * xs[1][d3], s1);
            s2 = fmaf(cv, xs[2][d1] * xs[2][d2] * xs[2][d3], s2);
            s3 = fmaf(cv, xs[3][d1] * xs[3][d2] * xs[3][d3], s3);
        }
        for (int i = l; i < 64; i += 32) {
            float cv = c2[(p << 6) + i];
            int d1 = (i >> 3) & 7, d2 = i & 7;
            s0 = fmaf(cv, xs[0][d1] * xs[0][d2], s0);
            s1 = fmaf(cv, xs[1][d1] * xs[1][d2], s1);
            s2 = fmaf(cv, xs[2][d1] * xs[2][d2], s2);
            s3 = fmaf(cv, xs[3][d1] * xs[3][d2], s3);
        }
        if (l < 8) {
            float cv = c1[(p << 3) + l];
            s0 = fmaf(cv, xs[0][l], s0);
            s1 = fmaf(cv, xs[1][l], s1);
            s2 = fmaf(cv, xs[2][l], s2);
            s3 = fmaf(cv, xs[3][l], s3);
        }
        redB[p][l][0] = s0; redB[p][l][1] = s1; redB[p][l][2] = s2; redB[p][l][3] = s3;
    }
    __syncthreads();
    if (t < 32) {
        int neu = t >> 3, p = t & 7;
        float tot = bias[p];
        #pragma unroll
        for (int g = 0; g < 8; ++g) tot += redA[g][t];
        for (int l = 0; l < 32; ++l) tot += redB[p][l][neu];
        out[t] = tot;
    }
}

extern "C" void kernel_launch(void* const* d_in, const int* in_sizes, int n_in,
                              void* d_out, int out_size, void* d_ws, size_t ws_size,
                              hipStream_t stream) {
    const float* X    = (const float*)d_in[0];
    const float* bias = (const float*)d_in[1];
    const float* c1   = (const float*)d_in[2];
    const float* c2   = (const float*)d_in[3];
    const float* c3   = (const float*)d_in[4];
    const float* c4   = (const float*)d_in[5];
    const float* c5   = (const float*)d_in[6];
    const float* c6   = (const float*)d_in[7];
    const float* c7   = (const float*)d_in[8];
    const float* c8   = (const float*)d_in[9];
    float* out = (float*)d_out;
    float* ws  = (float*)d_ws;

    int blocks = 1024;
    size_t maxb = ws_size / (32 * sizeof(float));
    if ((size_t)blocks > maxb) blocks = (int)maxb;
    if (blocks < 1) blocks = 1;

    poly_big<<<blocks, 512, 0, stream>>>(X, c4, c5, c6, c7, c8, ws);
    poly_final<<<1, 256, 0, stream>>>(X, bias, c1, c2, c3, ws, blocks, out);
}

// Round 2
// 169.089 us; speedup vs baseline: 3.3571x; 3.3571x over previous
//
#include <hip/hip_runtime.h>
#include <hip/hip_bf16.h>

// Segment enumeration: degrees 8,7,6,5,4 — each segment is 4096 contiguous
// floats of one polynomial row (16 KB). counts: 8*4096, 8*512, 8*64, 8*8, 8*1.
#define OFF7 32768
#define OFF6 36864
#define OFF5 37376
#define OFF4 37440
#define NSEG 37448

__device__ __forceinline__ float4 mul4(float4 a, float4 b) {
    return make_float4(a.x * b.x, a.y * b.y, a.z * b.z, a.w * b.w);
}
// d = s*b + c  (s scalar broadcast)
__device__ __forceinline__ float4 fma4s(float s, float4 b, float4 c) {
    return make_float4(fmaf(s, b.x, c.x), fmaf(s, b.y, c.y),
                       fmaf(s, b.z, c.z), fmaf(s, b.w, c.w));
}
// d = a*b + c  elementwise
__device__ __forceinline__ float4 fma44(float4 a, float4 b, float4 c) {
    return make_float4(fmaf(a.x, b.x, c.x), fmaf(a.y, b.y, c.y),
                       fmaf(a.z, b.z, c.z), fmaf(a.w, b.w, c.w));
}

// Degrees 4..8. Key identity: for element m = k*256 + l*4 + j of a 4096-float
// segment, kron^4[m] = T2[k*4 + (l>>4)] * T2[(l&15)*4 + j]. Low factor fixed
// per lane (registers), high factor is a broadcast LDS read (16 lanes/addr).
__global__ __launch_bounds__(512, 4) void poly_big(
    const float* __restrict__ X,
    const float* __restrict__ c4, const float* __restrict__ c5,
    const float* __restrict__ c6, const float* __restrict__ c7,
    const float* __restrict__ c8, float* __restrict__ ws)
{
    __shared__ float4 T1s[8], T2s[64];
    __shared__ float part[32];
    const int tid = threadIdx.x;

    if (tid < 8)  T1s[tid] = make_float4(X[tid], X[8 + tid], X[16 + tid], X[24 + tid]);
    if (tid < 32) part[tid] = 0.f;
    __syncthreads();
    if (tid < 64) T2s[tid] = mul4(T1s[tid >> 3], T1s[tid & 7]);
    __syncthreads();

    const int l = tid & 63;
    // per-lane fixed low factors: T2[(l&15)*4 + j]
    const float4 tl0 = T2s[((l & 15) << 2) + 0];
    const float4 tl1 = T2s[((l & 15) << 2) + 1];
    const float4 tl2 = T2s[((l & 15) << 2) + 2];
    const float4 tl3 = T2s[((l & 15) << 2) + 3];
    const int lhi = l >> 4;

    const int wid = (blockIdx.x * blockDim.x + tid) >> 6;
    const int W   = (gridDim.x * blockDim.x) >> 6;

    for (int g = wid; g < NSEG; g += W) {
        const float* src; int p, hi; float4 thseg;
        if (g < OFF7) {
            p = g >> 12; hi = g & 4095; src = c8 + ((size_t)p << 24);
            thseg = mul4(T2s[hi >> 6], T2s[hi & 63]);
        } else if (g < OFF6) {
            int s = g - OFF7; p = s >> 9; hi = s & 511; src = c7 + ((size_t)p << 21);
            thseg = mul4(T1s[hi >> 6], T2s[hi & 63]);
        } else if (g < OFF5) {
            int s = g - OFF6; p = s >> 6; hi = s & 63; src = c6 + ((size_t)p << 18);
            thseg = T2s[hi];
        } else if (g < OFF4) {
            int s = g - OFF5; p = s >> 3; hi = s & 7; src = c5 + ((size_t)p << 15);
            thseg = T1s[hi];
        } else {
            int s = g - OFF4; p = s; hi = 0; src = c4 + ((size_t)p << 12);
            thseg = make_float4(1.f, 1.f, 1.f, 1.f);
        }
        const float4* src4 = (const float4*)src + ((size_t)hi << 10) + l;

        // One clean streaming pass: 16 independent dwordx4 loads in flight.
        float4 buf[16];
        #pragma unroll
        for (int k = 0; k < 16; ++k) buf[k] = src4[(size_t)(k << 6)];

        float4 acc = make_float4(0.f, 0.f, 0.f, 0.f);
        #pragma unroll
        for (int k = 0; k < 16; ++k) {
            const float4 cv = buf[k];
            const float4 th = T2s[(k << 2) + lhi];   // broadcast read
            float4 inner = make_float4(cv.x * tl0.x, cv.x * tl0.y,
                                       cv.x * tl0.z, cv.x * tl0.w);
            inner = fma4s(cv.y, tl1, inner);
            inner = fma4s(cv.z, tl2, inner);
            inner = fma4s(cv.w, tl3, inner);
            acc = fma44(th, inner, acc);
        }

        float vx = acc.x * thseg.x, vy = acc.y * thseg.y,
              vz = acc.z * thseg.z, vw = acc.w * thseg.w;
        #pragma unroll
        for (int m = 32; m; m >>= 1) {
            vx += __shfl_xor(vx, m);
            vy += __shfl_xor(vy, m);
            vz += __shfl_xor(vz, m);
            vw += __shfl_xor(vw, m);
        }
        if (l == 0) {
            atomicAdd(&part[(p << 2) + 0], vx);
            atomicAdd(&part[(p << 2) + 1], vy);
            atomicAdd(&part[(p << 2) + 2], vz);
            atomicAdd(&part[(p << 2) + 3], vw);
        }
    }
    __syncthreads();
    // ws layout: [block][o] with o = neu*8 + p  (matches output layout)
    if (tid < 32) ws[(size_t)blockIdx.x * 32 + tid] = part[((tid & 7) << 2) + (tid >> 3)];
}

// Finalize: reduce block partials + bias + degrees 1..3.
__global__ __launch_bounds__(256) void poly_final(
    const float* __restrict__ X, const float* __restrict__ bias,
    const float* __restrict__ c1, const float* __restrict__ c2,
    const float* __restrict__ c3, const float* __restrict__ ws,
    int nblocks, float* __restrict__ out)
{
    __shared__ float xs[4][8];
    __shared__ float redA[8][32];
    __shared__ float redB[8][32][4];
    const int t = threadIdx.x;
    if (t < 32) xs[t >> 3][t & 7] = X[t];
    __syncthreads();

    // Phase A: sum the big-kernel partials. o = neu*8+p, 8 groups stride blocks.
    {
        int o = t & 31, g = t >> 5;
        float s = 0.f;
        for (int b = g; b < nblocks; b += 8) s += ws[(size_t)b * 32 + o];
        redA[g][o] = s;
    }
    // Phase B: degrees 1..3. p = t>>5, 32 lanes per polynomial.
    {
        int p = t >> 5, li = t & 31;
        float s0 = 0.f, s1 = 0.f, s2 = 0.f, s3 = 0.f;
        for (int i = li; i < 512; i += 32) {
            float cv = c3[(p << 9) + i];
            int d1 = (i >> 6) & 7, d2 = (i >> 3) & 7, d3 = i & 7;
            s0 = fmaf(cv, xs[0][d1] * xs[0][d2] * xs[0][d3], s0);
            s1 = fmaf(cv, xs[1][d1] * xs[1][d2] * xs[1][d3], s1);
            s2 = fmaf(cv, xs[2][d1] * xs[2][d2] * xs[2][d3], s2);
            s3 = fmaf(cv, xs[3][d1] * xs[3][d2] * xs[3][d3], s3);
        }
        for (int i = li; i < 64; i += 32) {
            float cv = c2[(p << 6) + i];
            int d1 = (i >> 3) & 7, d2 = i & 7;
            s0 = fmaf(cv, xs[0][d1] * xs[0][d2], s0);
            s1 = fmaf(cv, xs[1][d1] * xs[1][d2], s1);
            s2 = fmaf(cv, xs[2][d1] * xs[2][d2], s2);
            s3 = fmaf(cv, xs[3][d1] * xs[3][d2], s3);
        }
        if (li < 8) {
            float cv = c1[(p << 3) + li];
            s0 = fmaf(cv, xs[0][li], s0);
            s1 = fmaf(cv, xs[1][li], s1);
            s2 = fmaf(cv, xs[2][li], s2);
            s3 = fmaf(cv, xs[3][li], s3);
        }
        redB[p][li][0] = s0; redB[p][li][1] = s1; redB[p][li][2] = s2; redB[p][li][3] = s3;
    }
    __syncthreads();
    if (t < 32) {
        int neu = t >> 3, p = t & 7;
        float tot = bias[p];
        #pragma unroll
        for (int g = 0; g < 8; ++g) tot += redA[g][t];
        for (int li = 0; li < 32; ++li) tot += redB[p][li][neu];
        out[t] = tot;
    }
}

extern "C" void kernel_launch(void* const* d_in, const int* in_sizes, int n_in,
                              void* d_out, int out_size, void* d_ws, size_t ws_size,
                              hipStream_t stream) {
    const float* X    = (const float*)d_in[0];
    const float* bias = (const float*)d_in[1];
    const float* c1   = (const float*)d_in[2];
    const float* c2   = (const float*)d_in[3];
    const float* c3   = (const float*)d_in[4];
    const float* c4   = (const float*)d_in[5];
    const float* c5   = (const float*)d_in[6];
    const float* c6   = (const float*)d_in[7];
    const float* c7   = (const float*)d_in[8];
    const float* c8   = (const float*)d_in[9];
    float* out = (float*)d_out;
    float* ws  = (float*)d_ws;

    int blocks = 1024;
    size_t maxb = ws_size / (32 * sizeof(float));
    if ((size_t)blocks > maxb) blocks = (int)maxb;
    if (blocks < 1) blocks = 1;

    poly_big<<<blocks, 512, 0, stream>>>(X, c4, c5, c6, c7, c8, ws);
    poly_final<<<1, 256, 0, stream>>>(X, bias, c1, c2, c3, ws, blocks, out);
}